// Round 16
// baseline (441.991 us; speedup 1.0000x reference)
//
#include <hip/hip_runtime.h>

// Problem constants: N=262144 rows, NX=NQ=64, NU=16, fp32.
#define NROWS 262144
#define BT 256                 // threads/block (4 waves, no LDS, no barriers)
#define RPB 256                // rows/block: lane = row

// d_ws layout (floats) — two contiguous 9280-float phase blocks:
//  phase1 @0    : C1T[4096] | D11T[4096] | D12T[1024] | bv[64]
//  phase2 @9280 : AT [4096] | B1T [4096] | B2T [1024] | bx[64]
//  C1T[j*64+i]=C1[i][j]  D11T[i*64+k]=D11[k][i] (zeros at k<=i come from input)
//  D12T[j*64+i]=D12[i][j]  AT[j*64+k]=A[k][j]  B1T[i*64+k]=B1[k][i]
//  B2T[j*64+k]=B2[k][j]
// All tables are consumed COLUMN-wise at uniform (lane-independent)
// addresses -> the backend scalarizes them into s_load / SGPRs, and every
// FMA is v_fmac_f32 v_acc, s_m, v_x. No LDS anywhere in the fused kernel.
//
// Rationale (r7..r15 triangulation): the broadcast-based engine is pinned at
// 94% of its LDS-return floor (~123us) — each FMA drags 4B/lane of matrix
// through LDS. lane=row + SGPR matrix removes that stream entirely and
// makes the substitution lane-local (no broadcasts at all).

__global__ void prep_kernel(const float* __restrict__ A, const float* __restrict__ B1,
                            const float* __restrict__ B2, const float* __restrict__ C1,
                            const float* __restrict__ D11, const float* __restrict__ D12,
                            const float* __restrict__ bv, const float* __restrict__ bx,
                            float* __restrict__ ws) {
    int g = blockIdx.x * 256 + threadIdx.x;
    if (g < 4096) {
        int r = g >> 6, c = g & 63;       // source row r, col c (64x64 row-major)
        int to = c * 64 + r;
        ws[0     + to] = C1[g];           // C1T
        ws[4096  + to] = D11[g];          // D11T
        ws[9280  + to] = A[g];            // AT
        ws[13376 + to] = B1[g];           // B1T
    }
    if (g < 1024) {
        int r = g >> 4, c = g & 15;       // 64x16 row-major source
        int to = c * 64 + r;
        ws[8192  + to] = D12[g];          // D12T
        ws[17472 + to] = B2[g];           // B2T
    }
    if (g < 64) {
        ws[9216  + g] = bv[g];
        ws[18496 + g] = bx[g];
    }
}

// Pin pass boundaries: stops cross-pass live-range extension (r6: +70us).
__device__ __forceinline__ void fence_sched() { __builtin_amdgcn_sched_barrier(0); }

// Fused kernel, lane = row. Per lane:
//   P1: s[64] = bv + C1 x + D12 u       (x in 16-reg quarters; u 16 regs)
//   P2: lane-local forward substitution  (D11 cols from SGPRs) -> w in s[]
//   P3: out in 16-reg quarters: bx + B1 w + A x + B2 u
// Peak live: P3 = s(64) + acc(16) + xq(16) + addr ~= 100 < 128 cap.
// launch_bounds(256,4): cap = 2048/(4 blk * 4 waves) = 128; 16 waves/CU.
__global__ __launch_bounds__(BT, 4) void renl2_fused(const float* __restrict__ x,
                                                     const float* __restrict__ u,
                                                     const float* __restrict__ ws,
                                                     float* __restrict__ out) {
    const size_t row = (size_t)blockIdx.x * RPB + threadIdx.x;
    const float* __restrict__ xr = x + row * 64;
    const float* __restrict__ ur = u + row * 16;

    // ---- P1: s = bv + C1 x + D12 u ----
    float s[64];
#pragma unroll
    for (int i = 0; i < 64; i++) s[i] = ws[9216 + i];            // bv (SGPR)

#pragma unroll
    for (int q = 0; q < 4; q++) {
        const float* xp = xr + q * 16;
        asm volatile("" : "+v"(xp));      // launder: no CSE with later passes
        float xq[16];
        *(float4*)(xq)      = *(const float4*)(xp);
        *(float4*)(xq + 4)  = *(const float4*)(xp + 4);
        *(float4*)(xq + 8)  = *(const float4*)(xp + 8);
        *(float4*)(xq + 12) = *(const float4*)(xp + 12);
#pragma unroll
        for (int jj = 0; jj < 16; jj++) {
            const int j = q * 16 + jj;
#pragma unroll
            for (int i = 0; i < 64; i++)
                s[i] = fmaf(ws[j * 64 + i], xq[jj], s[i]);       // C1T @0
        }
    }
    {
        const float* up = ur;
        asm volatile("" : "+v"(up));
        float uu[16];
        *(float4*)(uu)      = *(const float4*)(up);
        *(float4*)(uu + 4)  = *(const float4*)(up + 4);
        *(float4*)(uu + 8)  = *(const float4*)(up + 8);
        *(float4*)(uu + 12) = *(const float4*)(up + 12);
#pragma unroll
        for (int j = 0; j < 16; j++)
#pragma unroll
            for (int i = 0; i < 64; i++)
                s[i] = fmaf(ws[8192 + j * 64 + i], uu[j], s[i]); // D12T @8192
    }
    fence_sched();

    // ---- P2: lane-local forward substitution (s -> w in place) ----
    // step i: w_i = relu(s_i); s_k += D11[k][i]*w_i for k>i
    // (D11T[i*64+k] = D11[k][i], contiguous tail, SGPR-loaded, K$-resident)
#pragma unroll
    for (int i = 0; i < 64; i++) {
        s[i] = fmaxf(s[i], 0.0f);
#pragma unroll
        for (int k = i + 1; k < 64; k++)
            s[k] = fmaf(ws[4096 + i * 64 + k], s[i], s[k]);      // D11T @4096
    }
    fence_sched();

    // ---- P3: out = bx + B1 w + A x + B2 u, in 16-output quarters ----
#pragma unroll
    for (int h = 0; h < 4; h++) {
        float acc[16];
#pragma unroll
        for (int ii = 0; ii < 16; ii++) acc[ii] = ws[18496 + h * 16 + ii]; // bx

        // B1·w : w is register-resident (s), coefficients SGPR
#pragma unroll
        for (int j = 0; j < 64; j++)
#pragma unroll
            for (int ii = 0; ii < 16; ii++)
                acc[ii] = fmaf(ws[13376 + j * 64 + h * 16 + ii], s[j], acc[ii]);

        // A·x : x re-read per quarter (L2-hot; laundered so quarters
        // don't CSE into one 64-reg x block — the r15 spill mechanism)
#pragma unroll
        for (int q = 0; q < 4; q++) {
            const float* xp = xr + q * 16;
            asm volatile("" : "+v"(xp));
            float xq[16];
            *(float4*)(xq)      = *(const float4*)(xp);
            *(float4*)(xq + 4)  = *(const float4*)(xp + 4);
            *(float4*)(xq + 8)  = *(const float4*)(xp + 8);
            *(float4*)(xq + 12) = *(const float4*)(xp + 12);
#pragma unroll
            for (int jj = 0; jj < 16; jj++) {
                const int j = q * 16 + jj;
#pragma unroll
                for (int ii = 0; ii < 16; ii++)
                    acc[ii] = fmaf(ws[9280 + j * 64 + h * 16 + ii], xq[jj], acc[ii]);
            }
        }
        // B2·u
        {
            const float* up = ur;
            asm volatile("" : "+v"(up));
            float uu[16];
            *(float4*)(uu)      = *(const float4*)(up);
            *(float4*)(uu + 4)  = *(const float4*)(up + 4);
            *(float4*)(uu + 8)  = *(const float4*)(up + 8);
            *(float4*)(uu + 12) = *(const float4*)(up + 12);
#pragma unroll
            for (int j = 0; j < 16; j++)
#pragma unroll
                for (int ii = 0; ii < 16; ii++)
                    acc[ii] = fmaf(ws[17472 + j * 64 + h * 16 + ii], uu[j], acc[ii]);
        }

        // store quarter (16 floats contiguous per lane)
        float* op = out + row * 64 + h * 16;
        *(float4*)(op)      = *(const float4*)(acc);
        *(float4*)(op + 4)  = *(const float4*)(acc + 4);
        *(float4*)(op + 8)  = *(const float4*)(acc + 8);
        *(float4*)(op + 12) = *(const float4*)(acc + 12);
        fence_sched();
    }
}

extern "C" void kernel_launch(void* const* d_in, const int* in_sizes, int n_in,
                              void* d_out, int out_size, void* d_ws, size_t ws_size,
                              hipStream_t stream) {
    const float* x   = (const float*)d_in[0];
    const float* u   = (const float*)d_in[1];
    const float* A   = (const float*)d_in[2];
    const float* B1  = (const float*)d_in[3];
    const float* B2  = (const float*)d_in[4];
    const float* C1  = (const float*)d_in[5];
    const float* D11 = (const float*)d_in[6];
    const float* D12 = (const float*)d_in[7];
    const float* bv  = (const float*)d_in[8];
    const float* bx  = (const float*)d_in[9];
    float* out = (float*)d_out;
    float* ws  = (float*)d_ws;

    prep_kernel<<<16, 256, 0, stream>>>(A, B1, B2, C1, D11, D12, bv, bx, ws);
    renl2_fused<<<NROWS / RPB, BT, 0, stream>>>(x, u, ws, out);
}